// Round 2
// baseline (11999.441 us; speedup 1.0000x reference)
//
#include <hip/hip_runtime.h>
#include <hip/hip_bf16.h>
#include <math.h>

#define TH 4            // tile height (y)
#define TW 8            // tile width  (x)
#define NPOS 32         // TH*TW positions per block
#define NUM_OC 160      // 150 real channels (24 loc + 126 conf) padded to 160
#define WS 161          // LDS weight row stride (odd -> conflict-free)
#define OS 33           // LDS out row stride (padded)
#define CC 8            // channel chunk staged per K-iteration
#define NUM_PRIORS 11640
#define OUT_CH 25       // 4 box + 21 classes
#define BATCH 32

union Smem {
  struct {
    float patch[CC * (TH + 2) * (TW + 2)];   // input patch
    float w[9 * CC * WS];                    // weights [tap][c][oc]
  } st;
  float outbuf[NUM_OC * OS];                 // conv results for epilogue
};

template <int C, int F>
__global__ __launch_bounds__(256)
void ssd_stage(const float* __restrict__ x,
               const float* __restrict__ loc_w, const float* __restrict__ loc_b,
               const float* __restrict__ conf_w, const float* __restrict__ conf_b,
               const float* __restrict__ priors,
               float* __restrict__ out, int stage_off)
{
  constexpr int nx = (F + TW - 1) / TW;
  constexpr int ny = (F + TH - 1) / TH;
  __shared__ Smem smem;

  const int bid = blockIdx.x;
  const int b   = bid / (nx * ny);
  const int rem = bid % (nx * ny);
  const int ty  = rem / nx;
  const int tx  = rem % nx;
  const int x0  = tx * TW;
  const int y0  = ty * TH;

  const int t = threadIdx.x;
  const int g = t & 31;    // oc group: handles oc = g, g+32, ..., g+128
  const int p = t >> 5;    // x-column within tile: 0..7

  float acc[5][TH] = {};   // [oc_u][y_v]

  #pragma unroll 1
  for (int c0 = 0; c0 < C; c0 += CC) {
    __syncthreads();
    // ---- stage input patch: CC channels x (TH+2) x (TW+2), zero-padded halo ----
    for (int i = t; i < CC * (TH + 2) * (TW + 2); i += 256) {
      int c  = i / ((TH + 2) * (TW + 2));
      int r  = i - c * ((TH + 2) * (TW + 2));
      int yy = r / (TW + 2);
      int xx = r - yy * (TW + 2);
      int gy = y0 + yy - 1;
      int gx = x0 + xx - 1;
      float v = 0.f;
      if (gy >= 0 && gy < F && gx >= 0 && gx < F)
        v = x[(((size_t)b * C + (c0 + c)) * F + gy) * F + gx];
      smem.st.patch[i] = v;
    }
    // ---- stage weights: [tap][c][oc] layout, oc 0..23 = loc, 24..149 = conf ----
    for (int i = t; i < NUM_OC * (CC * 9); i += 256) {
      int oc  = i / (CC * 9);
      int j   = i - oc * (CC * 9);
      int c   = j / 9;
      int tap = j - c * 9;
      float v = 0.f;
      if (oc < 24)        v = loc_w [((size_t)oc        * C + (c0 + c)) * 9 + tap];
      else if (oc < 150)  v = conf_w[((size_t)(oc - 24) * C + (c0 + c)) * 9 + tap];
      smem.st.w[(tap * CC + c) * WS + oc] = v;
    }
    __syncthreads();

    // ---- MAC loop: 9 taps x CC channels; 9 LDS x-reads per 20 FMAs per thread ----
    for (int tap = 0; tap < 9; ++tap) {
      const int ky = tap / 3;
      const int kx = tap - ky * 3;
      const int xbase = ky * (TW + 2) + kx + p;
      const int wbase = tap * CC * WS + g;
      #pragma unroll
      for (int c = 0; c < CC; ++c) {
        float xv[TH];
        #pragma unroll
        for (int v = 0; v < TH; ++v)
          xv[v] = smem.st.patch[c * ((TH + 2) * (TW + 2)) + v * (TW + 2) + xbase];
        #pragma unroll
        for (int u = 0; u < 5; ++u) {
          float wv = smem.st.w[wbase + c * WS + u * 32];
          #pragma unroll
          for (int v = 0; v < TH; ++v)
            acc[u][v] += wv * xv[v];
        }
      }
    }
  }

  // ---- epilogue: bias + transpose through LDS ----
  __syncthreads();
  #pragma unroll
  for (int u = 0; u < 5; ++u) {
    int oc = g + 32 * u;
    float bias = 0.f;
    if (oc < 24)       bias = loc_b[oc];
    else if (oc < 150) bias = conf_b[oc - 24];
    #pragma unroll
    for (int v = 0; v < TH; ++v)
      smem.outbuf[oc * OS + v * TW + p] = acc[u][v] + bias;
  }
  __syncthreads();

  // ---- softmax + prior decode: one thread per (position, anchor) ----
  if (t < NPOS * 6) {
    int pos = t / 6;
    int a   = t - pos * 6;
    int lx  = pos & 7;
    int ly  = pos >> 3;
    int gx  = x0 + lx;
    int gy  = y0 + ly;
    if (gx < F && gy < F) {
      float cls[21];
      float m = -1e30f;
      #pragma unroll
      for (int k = 0; k < 21; ++k) {
        cls[k] = smem.outbuf[(24 + a * 21 + k) * OS + pos];
        m = fmaxf(m, cls[k]);
      }
      float s = 0.f;
      #pragma unroll
      for (int k = 0; k < 21; ++k) { cls[k] = __expf(cls[k] - m); s += cls[k]; }
      float inv = 1.f / s;

      float l0 = smem.outbuf[(a * 4 + 0) * OS + pos];
      float l1 = smem.outbuf[(a * 4 + 1) * OS + pos];
      float l2 = smem.outbuf[(a * 4 + 2) * OS + pos];
      float l3 = smem.outbuf[(a * 4 + 3) * OS + pos];

      int prior = stage_off + (gy * F + gx) * 6 + a;
      const float* pr = priors + (size_t)prior * 4;
      float px = pr[0], py = pr[1], pw = pr[2], ph = pr[3];
      float cx = px + l0 * 0.1f * pw;
      float cy = py + l1 * 0.1f * ph;
      float w  = pw * __expf(l2 * 0.2f);
      float h  = ph * __expf(l3 * 0.2f);
      float minx = cx - 0.5f * w;
      float miny = cy - 0.5f * h;

      float* o = out + ((size_t)b * NUM_PRIORS + prior) * OUT_CH;
      o[0] = minx;
      o[1] = miny;
      o[2] = minx + w;
      o[3] = miny + h;
      #pragma unroll
      for (int k = 0; k < 21; ++k)
        o[4 + k] = cls[k] * inv;
    }
  }
}

template <int C, int F>
static void launch_stage(void* const* d_in, int base, const float* priors, float* out,
                         int stage_off, hipStream_t stream) {
  constexpr int nx = (F + TW - 1) / TW;
  constexpr int ny = (F + TH - 1) / TH;
  int blocks = BATCH * nx * ny;
  ssd_stage<C, F><<<blocks, 256, 0, stream>>>(
      (const float*)d_in[base + 0], (const float*)d_in[base + 1], (const float*)d_in[base + 2],
      (const float*)d_in[base + 3], (const float*)d_in[base + 4], priors, out, stage_off);
}

extern "C" void kernel_launch(void* const* d_in, const int* in_sizes, int n_in,
                              void* d_out, int out_size, void* d_ws, size_t ws_size,
                              hipStream_t stream) {
  // setup_inputs() dict order per stage s: feat, loc_w, loc_b, conf_w, conf_b; priors = d_in[30]
  const float* priors = (const float*)d_in[30];
  float* out = (float*)d_out;
  launch_stage<512,  38>(d_in,  0, priors, out,     0, stream);
  launch_stage<1024, 19>(d_in,  5, priors, out,  8664, stream);
  launch_stage<512,  10>(d_in, 10, priors, out, 10830, stream);
  launch_stage<256,   5>(d_in, 15, priors, out, 11430, stream);
  launch_stage<256,   3>(d_in, 20, priors, out, 11580, stream);
  launch_stage<256,   1>(d_in, 25, priors, out, 11634, stream);
}

// Round 3
// 617.133 us; speedup vs baseline: 19.4438x; 19.4438x over previous
//
#include <hip/hip_runtime.h>
#include <hip/hip_bf16.h>
#include <math.h>

typedef __attribute__((ext_vector_type(8))) short bf16x8;   // 8 bf16 = 4 VGPRs
typedef __attribute__((ext_vector_type(16))) float f32x16;  // 32x32 mfma acc

#define NUM_PRIORS 11640
#define OUT_CH 25
#define BATCH 32

// ---------------- workspace layout (bytes) ----------------
// bf16 transposed weights Wt[s][n=0..159][k=tap*C+c]
#define WT0 0u
#define WT1 1474560u
#define WT2 4423680u
#define WT3 5898240u
#define WT4 6635520u
#define WT5 7372800u
// fp32 conv output CONV[s][b][m=y*F+x][n=0..159]
#define CV0 8110080u
#define CV1 37683200u
#define CV2 45076480u
#define CV3 47124480u
#define CV4 47636480u
#define CV5 47820800u
#define WS_TOTAL 47841280u

// ================= weight prepass: fp32 OIHW -> bf16 [n][tap*C+c] =========
template <int C>
__global__ __launch_bounds__(256)
void wprep(const float* __restrict__ loc_w, const float* __restrict__ conf_w,
           __hip_bfloat16* __restrict__ wt)
{
  constexpr int K = 9 * C;
  int idx = blockIdx.x * 256 + threadIdx.x;
  if (idx >= 160 * K) return;
  int n   = idx / K;
  int r   = idx - n * K;
  int tap = r / C;
  int c   = r - tap * C;
  float v = 0.f;
  if (n < 24)        v = loc_w [((size_t)n        * C + c) * 9 + tap];
  else if (n < 150)  v = conf_w[((size_t)(n - 24) * C + c) * 9 + tap];
  wt[idx] = __float2bfloat16(v);
}

// ================= implicit-GEMM conv: C[m][n] += A[m][k] * Wt[k][n] ======
// block: 128 m x 160 n, 4 waves (each 32 m x 5 n-tiles of 32), BK=64
template <int C, int F, int SPLIT, bool ATOMIC>
__global__ __launch_bounds__(256)
void gemm_conv(const float* __restrict__ x, const __hip_bfloat16* __restrict__ wt,
               float* __restrict__ cv)
{
  constexpr int FF = F * F;
  constexpr int MB = (FF + 127) / 128;
  constexpr int CHUNKS = 9 * C / 64;   // C % 64 == 0 for all stages
  constexpr int K = 9 * C;

  const int bid = blockIdx.x;
  const int sp  = bid % SPLIT;
  const int mb  = (bid / SPLIT) % MB;
  const int b   = bid / (SPLIT * MB);
  const int ck0 = sp * CHUNKS / SPLIT;
  const int ck1 = (sp + 1) * CHUNKS / SPLIT;

  __shared__ __align__(16) unsigned short lA[128 * 72];  // [m][cc] bf16, stride 72
  __shared__ __align__(16) unsigned short lB[160 * 72];  // [n][cc] bf16, stride 72

  const int t    = threadIdx.x;
  const int wave = t >> 6;
  const int lane = t & 63;

  // A-staging mapping: thread stages row am, half ahalf (cc 0..31 / 32..63)
  const int am    = t & 127;
  const int ahalf = t >> 7;
  const int m_img = mb * 128 + am;
  const int ay    = m_img / F;          // constexpr divisor
  const int ax    = m_img - ay * F;
  const float* xb = x + (size_t)b * C * FF;

  // compute mapping
  const int cm    = lane & 31;          // m (A) / n (B) within tile
  const int khalf = lane >> 5;          // k: +0 / +8
  const int m_row = wave * 32 + cm;

  f32x16 acc[5];
  #pragma unroll
  for (int ntile = 0; ntile < 5; ++ntile)
    #pragma unroll
    for (int r = 0; r < 16; ++r) acc[ntile][r] = 0.f;

  for (int ck = ck0; ck < ck1; ++ck) {
    const int tap = (ck * 64) / C;      // chunk fully inside one tap
    const int c0  = ck * 64 - tap * C;
    const int dy  = tap / 3 - 1;
    const int dx  = tap - (tap / 3) * 3 - 1;

    // block-uniform chunk skip (image rows this block touches vs tap shift)
    {
      int ylo = (mb * 128) / F;
      int mhi = mb * 128 + 127; if (mhi > FF - 1) mhi = FF - 1;
      int yhi = mhi / F;
      bool any = (ylo + dy <= F - 1) && (yhi + dy >= 0) && (F >= 2 || dx == 0);
      if (!any) continue;               // uniform across block: barrier-safe
    }

    const int  yy = ay + dy, xx = ax + dx;
    const bool avalid = (m_img < FF) && (yy >= 0) && (yy < F) && (xx >= 0) && (xx < F);
    const int  aoff   = avalid ? (yy * F + xx) : 0;

    __syncthreads();  // previous compute done before restaging

    // ---- stage A: 4 x (8 coalesced fp32 loads -> pack -> ds_write_b128) ----
    #pragma unroll
    for (int j = 0; j < 4; ++j) {
      const int ccb = ahalf * 32 + j * 8;
      float v[8];
      #pragma unroll
      for (int q = 0; q < 8; ++q) {
        float raw = xb[(size_t)(c0 + ccb + q) * FF + aoff];
        v[q] = avalid ? raw : 0.f;
      }
      union { bf16x8 v8; __hip_bfloat162 h2[4]; } pk;
      #pragma unroll
      for (int q = 0; q < 4; ++q)
        pk.h2[q] = __float22bfloat162_rn(float2{v[2 * q], v[2 * q + 1]});
      *(bf16x8*)&lA[am * 72 + ccb] = pk.v8;
    }

    // ---- stage B: contiguous bf16 copy, b128 in / b128 out ----
    #pragma unroll
    for (int p = 0; p < 5; ++p) {
      const int e   = p * 256 + t;      // 0..1279
      const int n   = e >> 3;
      const int seg = e & 7;
      bf16x8 w8 = *(const bf16x8*)&wt[(size_t)n * K + ck * 64 + seg * 8];
      *(bf16x8*)&lB[n * 72 + seg * 8] = w8;
    }
    __syncthreads();

    // ---- compute: 4 ksubs x 5 ntiles MFMA ----
    #pragma unroll
    for (int ks = 0; ks < 4; ++ks) {
      bf16x8 af = *(const bf16x8*)&lA[m_row * 72 + ks * 16 + khalf * 8];
      #pragma unroll
      for (int ntile = 0; ntile < 5; ++ntile) {
        bf16x8 bfr = *(const bf16x8*)&lB[(ntile * 32 + cm) * 72 + ks * 16 + khalf * 8];
        acc[ntile] = __builtin_amdgcn_mfma_f32_32x32x16_bf16(af, bfr, acc[ntile], 0, 0, 0);
      }
    }
  }

  // ---- store / atomic-accumulate C ----
  float* cbase = cv + (size_t)b * FF * 160;
  #pragma unroll
  for (int ntile = 0; ntile < 5; ++ntile) {
    const int n = ntile * 32 + cm;
    #pragma unroll
    for (int r = 0; r < 16; ++r) {
      const int mm  = wave * 32 + (r & 3) + 8 * (r >> 2) + 4 * khalf;
      const int m_g = mb * 128 + mm;
      if (m_g < FF) {
        if (ATOMIC) atomicAdd(&cbase[(size_t)m_g * 160 + n], acc[ntile][r]);
        else        cbase[(size_t)m_g * 160 + n] = acc[ntile][r];
      }
    }
  }
}

// ================= decode: bias + softmax + prior decode ==================
struct DecArgs {
  const float* lb[6];
  const float* cb[6];
};

template <int F>
__device__ __forceinline__
void dec_one(int local, int b, const float* cvs, const float* lb, const float* cb,
             const float* p4, float* o)
{
  constexpr int FF = F * F;
  const int pos = local / 6;
  const int a   = local - pos * 6;
  const float* strip = cvs + ((size_t)b * FF + pos) * 160;

  float cls[21];
  float mx = -1e30f;
  #pragma unroll
  for (int k = 0; k < 21; ++k) {
    cls[k] = strip[24 + a * 21 + k] + cb[a * 21 + k];
    mx = fmaxf(mx, cls[k]);
  }
  float s = 0.f;
  #pragma unroll
  for (int k = 0; k < 21; ++k) { cls[k] = __expf(cls[k] - mx); s += cls[k]; }
  const float inv = 1.f / s;

  const float l0 = strip[a * 4 + 0] + lb[a * 4 + 0];
  const float l1 = strip[a * 4 + 1] + lb[a * 4 + 1];
  const float l2 = strip[a * 4 + 2] + lb[a * 4 + 2];
  const float l3 = strip[a * 4 + 3] + lb[a * 4 + 3];

  const float px = p4[0], py = p4[1], pw = p4[2], ph = p4[3];
  const float cx = px + l0 * 0.1f * pw;
  const float cy = py + l1 * 0.1f * ph;
  const float w  = pw * __expf(l2 * 0.2f);
  const float h  = ph * __expf(l3 * 0.2f);
  const float minx = cx - 0.5f * w;
  const float miny = cy - 0.5f * h;

  o[0] = minx; o[1] = miny; o[2] = minx + w; o[3] = miny + h;
  #pragma unroll
  for (int k = 0; k < 21; ++k) o[4 + k] = cls[k] * inv;
}

__global__ __launch_bounds__(256)
void decode_k(const char* __restrict__ wsb, DecArgs da,
              const float* __restrict__ priors, float* __restrict__ out)
{
  const int gid = blockIdx.x * 256 + threadIdx.x;
  if (gid >= BATCH * NUM_PRIORS) return;
  const int b  = gid / NUM_PRIORS;
  const int pr = gid - b * NUM_PRIORS;
  float* o = out + (size_t)gid * OUT_CH;
  const float* p4 = priors + (size_t)pr * 4;

  if (pr < 8664)       dec_one<38>(pr,         b, (const float*)(wsb + CV0), da.lb[0], da.cb[0], p4, o);
  else if (pr < 10830) dec_one<19>(pr - 8664,  b, (const float*)(wsb + CV1), da.lb[1], da.cb[1], p4, o);
  else if (pr < 11430) dec_one<10>(pr - 10830, b, (const float*)(wsb + CV2), da.lb[2], da.cb[2], p4, o);
  else if (pr < 11580) dec_one<5> (pr - 11430, b, (const float*)(wsb + CV3), da.lb[3], da.cb[3], p4, o);
  else if (pr < 11634) dec_one<3> (pr - 11580, b, (const float*)(wsb + CV4), da.lb[4], da.cb[4], p4, o);
  else                 dec_one<1> (pr - 11634, b, (const float*)(wsb + CV5), da.lb[5], da.cb[5], p4, o);
}

// ================= fallback (round-1 direct kernel, known-good) ===========
#define TH 4
#define TW 8
#define NPOS 32
#define NUM_OC 160
#define WS_STRIDE 161
#define OS 33
#define CC 8

union SmemFB {
  struct {
    float patch[CC * (TH + 2) * (TW + 2)];
    float w[9 * CC * WS_STRIDE];
  } st;
  float outbuf[NUM_OC * OS];
};

template <int C, int F>
__global__ __launch_bounds__(256)
void ssd_stage(const float* __restrict__ x,
               const float* __restrict__ loc_w, const float* __restrict__ loc_b,
               const float* __restrict__ conf_w, const float* __restrict__ conf_b,
               const float* __restrict__ priors,
               float* __restrict__ out, int stage_off)
{
  constexpr int nx = (F + TW - 1) / TW;
  constexpr int ny = (F + TH - 1) / TH;
  __shared__ SmemFB smem;

  const int bid = blockIdx.x;
  const int b   = bid / (nx * ny);
  const int rem = bid % (nx * ny);
  const int ty  = rem / nx;
  const int tx  = rem % nx;
  const int x0  = tx * TW;
  const int y0  = ty * TH;

  const int t = threadIdx.x;
  const int g = t & 31;
  const int p = t >> 5;

  float acc[5][TH] = {};

  #pragma unroll 1
  for (int c0 = 0; c0 < C; c0 += CC) {
    __syncthreads();
    for (int i = t; i < CC * (TH + 2) * (TW + 2); i += 256) {
      int c  = i / ((TH + 2) * (TW + 2));
      int r  = i - c * ((TH + 2) * (TW + 2));
      int yy = r / (TW + 2);
      int xx = r - yy * (TW + 2);
      int gy = y0 + yy - 1;
      int gx = x0 + xx - 1;
      float v = 0.f;
      if (gy >= 0 && gy < F && gx >= 0 && gx < F)
        v = x[(((size_t)b * C + (c0 + c)) * F + gy) * F + gx];
      smem.st.patch[i] = v;
    }
    for (int i = t; i < NUM_OC * (CC * 9); i += 256) {
      int oc  = i / (CC * 9);
      int j   = i - oc * (CC * 9);
      int c   = j / 9;
      int tap = j - c * 9;
      float v = 0.f;
      if (oc < 24)        v = loc_w [((size_t)oc        * C + (c0 + c)) * 9 + tap];
      else if (oc < 150)  v = conf_w[((size_t)(oc - 24) * C + (c0 + c)) * 9 + tap];
      smem.st.w[(tap * CC + c) * WS_STRIDE + oc] = v;
    }
    __syncthreads();

    for (int tap = 0; tap < 9; ++tap) {
      const int ky = tap / 3;
      const int kx = tap - ky * 3;
      const int xbase = ky * (TW + 2) + kx + p;
      const int wbase = tap * CC * WS_STRIDE + g;
      #pragma unroll
      for (int c = 0; c < CC; ++c) {
        float xv[TH];
        #pragma unroll
        for (int v = 0; v < TH; ++v)
          xv[v] = smem.st.patch[c * ((TH + 2) * (TW + 2)) + v * (TW + 2) + xbase];
        #pragma unroll
        for (int u = 0; u < 5; ++u) {
          float wv = smem.st.w[wbase + c * WS_STRIDE + u * 32];
          #pragma unroll
          for (int v = 0; v < TH; ++v)
            acc[u][v] += wv * xv[v];
        }
      }
    }
  }

  __syncthreads();
  #pragma unroll
  for (int u = 0; u < 5; ++u) {
    int oc = g + 32 * u;
    float bias = 0.f;
    if (oc < 24)       bias = loc_b[oc];
    else if (oc < 150) bias = conf_b[oc - 24];
    #pragma unroll
    for (int v = 0; v < TH; ++v)
      smem.outbuf[oc * OS + v * TW + p] = acc[u][v] + bias;
  }
  __syncthreads();

  if (t < NPOS * 6) {
    int pos = t / 6;
    int a   = t - pos * 6;
    int lx  = pos & 7;
    int ly  = pos >> 3;
    int gx  = x0 + lx;
    int gy  = y0 + ly;
    if (gx < F && gy < F) {
      float cls[21];
      float m = -1e30f;
      #pragma unroll
      for (int k = 0; k < 21; ++k) {
        cls[k] = smem.outbuf[(24 + a * 21 + k) * OS + pos];
        m = fmaxf(m, cls[k]);
      }
      float s = 0.f;
      #pragma unroll
      for (int k = 0; k < 21; ++k) { cls[k] = __expf(cls[k] - m); s += cls[k]; }
      float inv = 1.f / s;

      float l0 = smem.outbuf[(a * 4 + 0) * OS + pos];
      float l1 = smem.outbuf[(a * 4 + 1) * OS + pos];
      float l2 = smem.outbuf[(a * 4 + 2) * OS + pos];
      float l3 = smem.outbuf[(a * 4 + 3) * OS + pos];

      int prior = stage_off + (gy * F + gx) * 6 + a;
      const float* pr = priors + (size_t)prior * 4;
      float px = pr[0], py = pr[1], pw = pr[2], ph = pr[3];
      float cx = px + l0 * 0.1f * pw;
      float cy = py + l1 * 0.1f * ph;
      float w  = pw * __expf(l2 * 0.2f);
      float h  = ph * __expf(l3 * 0.2f);
      float minx = cx - 0.5f * w;
      float miny = cy - 0.5f * h;

      float* o = out + ((size_t)b * NUM_PRIORS + prior) * OUT_CH;
      o[0] = minx;
      o[1] = miny;
      o[2] = minx + w;
      o[3] = miny + h;
      #pragma unroll
      for (int k = 0; k < 21; ++k)
        o[4 + k] = cls[k] * inv;
    }
  }
}

template <int C, int F>
static void launch_stage_fb(void* const* d_in, int base, const float* priors, float* out,
                            int stage_off, hipStream_t stream) {
  constexpr int nx = (F + TW - 1) / TW;
  constexpr int ny = (F + TH - 1) / TH;
  int blocks = BATCH * nx * ny;
  ssd_stage<C, F><<<blocks, 256, 0, stream>>>(
      (const float*)d_in[base + 0], (const float*)d_in[base + 1], (const float*)d_in[base + 2],
      (const float*)d_in[base + 3], (const float*)d_in[base + 4], priors, out, stage_off);
}

// ================= launch =================================================
extern "C" void kernel_launch(void* const* d_in, const int* in_sizes, int n_in,
                              void* d_out, int out_size, void* d_ws, size_t ws_size,
                              hipStream_t stream) {
  (void)in_sizes; (void)n_in; (void)out_size;
  const float* priors = (const float*)d_in[30];
  float* out = (float*)d_out;

  if (ws_size < (size_t)WS_TOTAL) {   // deterministic fallback: direct kernels
    launch_stage_fb<512,  38>(d_in,  0, priors, out,     0, stream);
    launch_stage_fb<1024, 19>(d_in,  5, priors, out,  8664, stream);
    launch_stage_fb<512,  10>(d_in, 10, priors, out, 10830, stream);
    launch_stage_fb<256,   5>(d_in, 15, priors, out, 11430, stream);
    launch_stage_fb<256,   3>(d_in, 20, priors, out, 11580, stream);
    launch_stage_fb<256,   1>(d_in, 25, priors, out, 11634, stream);
    return;
  }

  char* wsb = (char*)d_ws;

  // weight prepass (bf16 transpose), one launch per stage
  wprep<512> <<<(160 * 9 * 512  + 255) / 256, 256, 0, stream>>>((const float*)d_in[1],  (const float*)d_in[3],  (__hip_bfloat16*)(wsb + WT0));
  wprep<1024><<<(160 * 9 * 1024 + 255) / 256, 256, 0, stream>>>((const float*)d_in[6],  (const float*)d_in[8],  (__hip_bfloat16*)(wsb + WT1));
  wprep<512> <<<(160 * 9 * 512  + 255) / 256, 256, 0, stream>>>((const float*)d_in[11], (const float*)d_in[13], (__hip_bfloat16*)(wsb + WT2));
  wprep<256> <<<(160 * 9 * 256  + 255) / 256, 256, 0, stream>>>((const float*)d_in[16], (const float*)d_in[18], (__hip_bfloat16*)(wsb + WT3));
  wprep<256> <<<(160 * 9 * 256  + 255) / 256, 256, 0, stream>>>((const float*)d_in[21], (const float*)d_in[23], (__hip_bfloat16*)(wsb + WT4));
  wprep<256> <<<(160 * 9 * 256  + 255) / 256, 256, 0, stream>>>((const float*)d_in[26], (const float*)d_in[28], (__hip_bfloat16*)(wsb + WT5));

  // zero the atomic-accumulated conv regions (stages 1..5)
  hipMemsetAsync(wsb + CV1, 0, WS_TOTAL - CV1, stream);

  // implicit-GEMM convs
  gemm_conv<512,  38, 1, false><<<32 * 12,    256, 0, stream>>>((const float*)d_in[0],  (const __hip_bfloat16*)(wsb + WT0), (float*)(wsb + CV0));
  gemm_conv<1024, 19, 4, true> <<<32 * 3 * 4, 256, 0, stream>>>((const float*)d_in[5],  (const __hip_bfloat16*)(wsb + WT1), (float*)(wsb + CV1));
  gemm_conv<512,  10, 8, true> <<<32 * 8,     256, 0, stream>>>((const float*)d_in[10], (const __hip_bfloat16*)(wsb + WT2), (float*)(wsb + CV2));
  gemm_conv<256,   5, 8, true> <<<32 * 8,     256, 0, stream>>>((const float*)d_in[15], (const __hip_bfloat16*)(wsb + WT3), (float*)(wsb + CV3));
  gemm_conv<256,   3, 8, true> <<<32 * 8,     256, 0, stream>>>((const float*)d_in[20], (const __hip_bfloat16*)(wsb + WT4), (float*)(wsb + CV4));
  gemm_conv<256,   1, 4, true> <<<32 * 4,     256, 0, stream>>>((const float*)d_in[25], (const __hip_bfloat16*)(wsb + WT5), (float*)(wsb + CV5));

  // epilogue: bias + softmax + decode
  DecArgs da;
  da.lb[0] = (const float*)d_in[2];  da.cb[0] = (const float*)d_in[4];
  da.lb[1] = (const float*)d_in[7];  da.cb[1] = (const float*)d_in[9];
  da.lb[2] = (const float*)d_in[12]; da.cb[2] = (const float*)d_in[14];
  da.lb[3] = (const float*)d_in[17]; da.cb[3] = (const float*)d_in[19];
  da.lb[4] = (const float*)d_in[22]; da.cb[4] = (const float*)d_in[24];
  da.lb[5] = (const float*)d_in[27]; da.cb[5] = (const float*)d_in[29];
  decode_k<<<(BATCH * NUM_PRIORS + 255) / 256, 256, 0, stream>>>((const char*)d_ws, da, priors, out);
}